// Round 1
// baseline (5487.436 us; speedup 1.0000x reference)
//
#include <hip/hip_runtime.h>

// DefSeq R2: persistent cooperative-style recurrence (weights pinned in LDS,
// 3 tree-barriers/step) + bank-conflict-free k_gemm_out (XOR swizzle).

typedef __bf16 bf16;
typedef __bf16 bf16x8 __attribute__((ext_vector_type(8)));
typedef __bf16 bf16x4v __attribute__((ext_vector_type(4)));
typedef float f32x4 __attribute__((ext_vector_type(4)));

#define Vv 32000
#define Ee 512
#define Hh 1024
#define Ss 32
#define Bb 32
#define KC 1536

#define MFMA16(a, b, c) __builtin_amdgcn_mfma_f32_16x16x32_bf16(a, b, c, 0, 0, 0)

static __device__ __forceinline__ float sigf(float x) { return 1.0f / (1.0f + __expf(-x)); }

// ---------------- weight conversion ----------------

// Permuted gate weights: row g = 4*k + s  <->  source row s*1024 + k (s = i,f,g,o slab).
// cols [0,512) = Wih, cols [512,1536) = Whh.  Also bg[g] = bih+bhh (permuted).
__global__ void k_conv_gates(const float* __restrict__ Wih, const float* __restrict__ Whh,
                             const float* __restrict__ bih, const float* __restrict__ bhh,
                             bf16* __restrict__ Wgh, bf16* __restrict__ Wgl,
                             float* __restrict__ bg) {
  int g = blockIdx.y;
  int col = blockIdx.x * 256 + threadIdx.x;
  int k = g >> 2, s = g & 3;
  int src = s * Hh + k;
  float v = (col < Ee) ? Wih[(size_t)src * Ee + col] : Whh[(size_t)src * Hh + (col - Ee)];
  bf16 h = (bf16)v;
  Wgh[(size_t)g * KC + col] = h;
  Wgl[(size_t)g * KC + col] = (bf16)(v - (float)h);
  if (col == 0) bg[g] = bih[src] + bhh[src];
}

// [Wz;Wr] rows, cols [512,1536) only (h-part; we-part handled by k_zrwe precompute)
__global__ void k_conv_zr2(const float* __restrict__ Wz, const float* __restrict__ Wr,
                           bf16* __restrict__ W2h, bf16* __restrict__ W2l) {
  int j = blockIdx.y;                        // 0..1535
  int col = blockIdx.x * 256 + threadIdx.x;  // 0..1023 -> src col 512+col
  float v = (j < Hh) ? Wz[(size_t)j * KC + Ee + col] : Wr[(size_t)(j - Hh) * KC + Ee + col];
  bf16 h = (bf16)v;
  W2h[(size_t)j * Hh + col] = h;
  W2l[(size_t)j * Hh + col] = (bf16)(v - (float)h);
}

__global__ void k_conv_wh(const float* __restrict__ A, bf16* __restrict__ hi,
                          bf16* __restrict__ lo) {
  int j = blockIdx.y;
  int k = blockIdx.x * 256 + threadIdx.x;
  float v = A[(size_t)j * KC + k];
  bf16 h = (bf16)v;
  hi[(size_t)j * KC + k] = h;
  lo[(size_t)j * KC + k] = (bf16)(v - (float)h);
}

// ---------------- gathers / init ----------------

__global__ void k_gather_we(const int* __restrict__ word, const float* __restrict__ emb,
                            float* __restrict__ we) {
  int b = blockIdx.y;
  int e = blockIdx.x * 256 + threadIdx.x;
  we[b * Ee + e] = emb[(size_t)word[b] * Ee + e];
}

__global__ void k_gather_se(const int* __restrict__ seq, const float* __restrict__ emb,
                            bf16* __restrict__ se_h, bf16* __restrict__ se_l) {
  int tb = blockIdx.y;  // t*32 + b
  int e = blockIdx.x * 256 + threadIdx.x;
  float v = emb[(size_t)seq[tb] * Ee + e];
  bf16 h = (bf16)v;
  se_h[(size_t)tb * Ee + e] = h;
  se_l[(size_t)tb * Ee + e] = (bf16)(v - (float)h);
}

// h0 = we @ Wl.T + bl ; c = h0 ; (h_h,h_l) = bf16split(h0)
__global__ void k_init_h0(const float* __restrict__ we, const float* __restrict__ Wl,
                          const float* __restrict__ bl, float* __restrict__ c,
                          bf16* __restrict__ h_h, bf16* __restrict__ h_l) {
  int o = blockIdx.x * 4 + (threadIdx.x >> 6);  // 0..32767
  int lane = threadIdx.x & 63;
  int b = o >> 10, n = o & 1023;
  const float* wr = we + b * Ee;
  const float* wl = Wl + (size_t)n * Ee;
  int e0 = lane * 8;
  float4 a0 = *(const float4*)(wr + e0);
  float4 a1 = *(const float4*)(wr + e0 + 4);
  float4 b0 = *(const float4*)(wl + e0);
  float4 b1 = *(const float4*)(wl + e0 + 4);
  float s = a0.x * b0.x + a0.y * b0.y + a0.z * b0.z + a0.w * b0.w +
            a1.x * b1.x + a1.y * b1.y + a1.z * b1.z + a1.w * b1.w;
  for (int off = 32; off; off >>= 1) s += __shfl_down(s, off);
  if (lane == 0) {
    s += bl[n];
    c[o] = s;
    bf16 h = (bf16)s;
    h_h[o] = h;
    h_l[o] = (bf16)(s - (float)h);
  }
}

// zrwe[b][j] = we . [Wz;Wr][j][0:512] + (bz|br)[j]   (time-invariant; fp32, 3-term)
__global__ __launch_bounds__(256) void k_zrwe(const float* __restrict__ we,
                                              const float* __restrict__ Wz,
                                              const float* __restrict__ Wr,
                                              const float* __restrict__ bz,
                                              const float* __restrict__ br,
                                              float* __restrict__ zrwe) {
  int tid = threadIdx.x;
  int w = tid >> 6, lane = tid & 63, l16 = lane & 15, quad = lane >> 4;
  int j0 = (blockIdx.x * 4 + w) * 16;
  int j = j0 + l16;
  const float* wrow = (j < Hh) ? (Wz + (size_t)j * KC) : (Wr + (size_t)(j - Hh) * KC);
  f32x4 acc[2];
  acc[0] = (f32x4){0.f, 0.f, 0.f, 0.f};
  acc[1] = (f32x4){0.f, 0.f, 0.f, 0.f};
  for (int kk = 0; kk < Ee; kk += 32) {
    bf16x8 bh, bl;
#pragma unroll
    for (int i = 0; i < 8; ++i) {
      float v = wrow[kk + quad * 8 + i];
      bf16 hv = (bf16)v;
      bh[i] = hv;
      bl[i] = (bf16)(v - (float)hv);
    }
#pragma unroll
    for (int mt = 0; mt < 2; ++mt) {
      bf16x8 ah, al;
      const float* arow = we + (size_t)(mt * 16 + l16) * Ee + kk + quad * 8;
#pragma unroll
      for (int i = 0; i < 8; ++i) {
        float v = arow[i];
        bf16 hv = (bf16)v;
        ah[i] = hv;
        al[i] = (bf16)(v - (float)hv);
      }
      acc[mt] = MFMA16(ah, bh, acc[mt]);
      acc[mt] = MFMA16(al, bh, acc[mt]);
      acc[mt] = MFMA16(ah, bl, acc[mt]);
    }
  }
  float bias = (j < Hh) ? bz[j] : br[j - Hh];
#pragma unroll
  for (int mt = 0; mt < 2; ++mt)
#pragma unroll
    for (int r = 0; r < 4; ++r) {
      int b = mt * 16 + quad * 4 + r;
      zrwe[b * KC + j] = acc[mt][r] + bias;
    }
}

// ---------------- persistent recurrence ----------------

struct RecurArgs {
  const bf16 *Wgh, *Wgl;    // [4096][1536] permuted gate weights
  const bf16 *W2h, *W2l;    // [1536][1024] [Wz;Wr] h-part
  const bf16 *Whh2, *Whl2;  // [1024][1536] Wh
  const bf16 *seh, *sel;    // [1024][512]
  const float *bg;          // [4096] permuted gate bias
  const float *bhb;         // [1024]
  const float *zrwe;        // [32][1536]
  const float *we;          // [32][512]
  bf16 *h_h, *h_l;          // [32][1024] recurrent h (hi/lo)
  float *c, *hl, *z, *hf;   // [32][1024] each
  bf16 *hlh, *hll;          // [32][1024] h_lstm hi/lo
  bf16 *rweh, *rwel;        // [32][512]
  bf16 *hs;                 // [1024][1024] bf16 hidden states for out-proj
  unsigned *bar;            // barrier state (zeroed per launch)
};

// tree grid barrier: 8 groups x 32 blocks, agent-scope atomics (cross-XCD safe)
static __device__ __forceinline__ void gridbar(unsigned* bar, int blk) {
  __syncthreads();
  if (threadIdx.x == 0) {
    __threadfence();  // make this block's writes visible at agent scope
    unsigned g = __hip_atomic_load(bar + 144, __ATOMIC_RELAXED, __HIP_MEMORY_SCOPE_AGENT);
    unsigned v = __hip_atomic_fetch_add(bar + (blk >> 5) * 16, 1u, __ATOMIC_ACQ_REL,
                                        __HIP_MEMORY_SCOPE_AGENT);
    bool rel = false;
    if (v == 31u) {
      unsigned v2 =
          __hip_atomic_fetch_add(bar + 128, 1u, __ATOMIC_ACQ_REL, __HIP_MEMORY_SCOPE_AGENT);
      if (v2 == 7u) {
        rel = true;
#pragma unroll
        for (int i = 0; i < 8; ++i)
          __hip_atomic_store(bar + i * 16, 0u, __ATOMIC_RELAXED, __HIP_MEMORY_SCOPE_AGENT);
        __hip_atomic_store(bar + 128, 0u, __ATOMIC_RELAXED, __HIP_MEMORY_SCOPE_AGENT);
        __hip_atomic_store(bar + 144, g + 1u, __ATOMIC_RELEASE, __HIP_MEMORY_SCOPE_AGENT);
      }
    }
    if (!rel) {
      while (__hip_atomic_load(bar + 144, __ATOMIC_ACQUIRE, __HIP_MEMORY_SCOPE_AGENT) == g)
        __builtin_amdgcn_s_sleep(4);
    }
  }
  __syncthreads();
}

// grid = 256 blocks x 256 threads. LDS 136.5KB forces 1 block/CU -> all resident.
// Roles: all blocks: gates tile blk (16 permuted gate rows = 4 k-cols x 4 slabs).
//        blk<96: zr tile blk. 96<=blk<160: hh tile blk-96.
__global__ __launch_bounds__(256, 1) void k_recur(RecurArgs a) {
  __shared__ __align__(16) bf16 sWa[2][16 * 1024];  // gates: Wg cols [512,1536)
  __shared__ __align__(16) bf16 sWx[2][16 * 1024];  // zr h-part / Wh cols [512,1536)
  __shared__ float red[4][32][17];

  int blk = blockIdx.x, tid = threadIdx.x;
  int w = tid >> 6, lane = tid & 63, l16 = lane & 15, quad = lane >> 4;

  // stage persistent weight slices into LDS, XOR-swizzled (2-way conflict = free)
  for (int i = tid; i < 2048; i += 256) {
    int row = i >> 7, ch = i & 127, e = ch * 8;
    int d = row * 1024 + (e ^ ((row & 7) << 3));
    *(bf16x8*)&sWa[0][d] = *(const bf16x8*)&a.Wgh[(size_t)(blk * 16 + row) * KC + Ee + e];
    *(bf16x8*)&sWa[1][d] = *(const bf16x8*)&a.Wgl[(size_t)(blk * 16 + row) * KC + Ee + e];
    if (blk < 96) {
      *(bf16x8*)&sWx[0][d] = *(const bf16x8*)&a.W2h[(size_t)(blk * 16 + row) * Hh + e];
      *(bf16x8*)&sWx[1][d] = *(const bf16x8*)&a.W2l[(size_t)(blk * 16 + row) * Hh + e];
    } else if (blk < 160) {
      *(bf16x8*)&sWx[0][d] =
          *(const bf16x8*)&a.Whh2[(size_t)((blk - 96) * 16 + row) * KC + Ee + e];
      *(bf16x8*)&sWx[1][d] =
          *(const bf16x8*)&a.Whl2[(size_t)((blk - 96) * 16 + row) * KC + Ee + e];
    }
  }
  __syncthreads();

  for (int t = 0; t < Ss; ++t) {
    // ===== phase A: gates tile = [se_t | h] @ Wg[blk]^T, then LSTM pointwise =====
    {
      f32x4 acc[2];
      acc[0] = (f32x4){0.f, 0.f, 0.f, 0.f};
      acc[1] = (f32x4){0.f, 0.f, 0.f, 0.f};
#pragma unroll
      for (int it = 0; it < 12; ++it) {
        int kk = w * 384 + it * 32;
        bf16x8 bh, bl;
        if (kk < Ee) {
          bh = *(const bf16x8*)&a.Wgh[(size_t)(blk * 16 + l16) * KC + kk + quad * 8];
          bl = *(const bf16x8*)&a.Wgl[(size_t)(blk * 16 + l16) * KC + kk + quad * 8];
        } else {
          int eo = (kk - Ee) + quad * 8;
          int d = l16 * 1024 + (eo ^ ((l16 & 7) << 3));
          bh = *(const bf16x8*)&sWa[0][d];
          bl = *(const bf16x8*)&sWa[1][d];
        }
#pragma unroll
        for (int mt = 0; mt < 2; ++mt) {
          int b = mt * 16 + l16;
          bf16x8 ah, al;
          if (kk < Ee) {
            ah = *(const bf16x8*)&a.seh[(size_t)(t * Bb + b) * Ee + kk + quad * 8];
            al = *(const bf16x8*)&a.sel[(size_t)(t * Bb + b) * Ee + kk + quad * 8];
          } else {
            ah = *(const bf16x8*)&a.h_h[(size_t)b * Hh + (kk - Ee) + quad * 8];
            al = *(const bf16x8*)&a.h_l[(size_t)b * Hh + (kk - Ee) + quad * 8];
          }
          acc[mt] = MFMA16(ah, bh, acc[mt]);
          acc[mt] = MFMA16(al, bh, acc[mt]);
          acc[mt] = MFMA16(ah, bl, acc[mt]);
        }
      }
#pragma unroll
      for (int mt = 0; mt < 2; ++mt)
#pragma unroll
        for (int r = 0; r < 4; ++r) red[w][mt * 16 + quad * 4 + r][l16] = acc[mt][r];
    }
    __syncthreads();
    if (tid < 128) {
      int b = tid >> 2, kl = tid & 3;
      float g4[4];
#pragma unroll
      for (int s = 0; s < 4; ++s) {
        int jl = kl * 4 + s;  // permuted tile row -> (k_local=kl, slab=s)
        g4[s] = red[0][b][jl] + red[1][b][jl] + red[2][b][jl] + red[3][b][jl] +
                a.bg[blk * 16 + jl];
      }
      int idx = b * Hh + blk * 4 + kl;
      float cn = sigf(g4[1]) * a.c[idx] + sigf(g4[0]) * tanhf(g4[2]);
      float hv = sigf(g4[3]) * tanhf(cn);
      a.c[idx] = cn;
      a.hl[idx] = hv;
      bf16 hb = (bf16)hv;
      a.hlh[idx] = hb;
      a.hll[idx] = (bf16)(hv - (float)hb);
    }
    gridbar(a.bar, blk);

    // ===== phase B: [z;r] tile = zrwe + h_lstm @ W2[blk]^T ; r*we -> rwe =====
    if (blk < 96) {
      f32x4 acc[2];
      acc[0] = (f32x4){0.f, 0.f, 0.f, 0.f};
      acc[1] = (f32x4){0.f, 0.f, 0.f, 0.f};
#pragma unroll
      for (int it = 0; it < 8; ++it) {
        int kk = w * 256 + it * 32;
        int eo = kk + quad * 8;
        int d = l16 * 1024 + (eo ^ ((l16 & 7) << 3));
        bf16x8 bh = *(const bf16x8*)&sWx[0][d];
        bf16x8 bl = *(const bf16x8*)&sWx[1][d];
#pragma unroll
        for (int mt = 0; mt < 2; ++mt) {
          int b = mt * 16 + l16;
          bf16x8 ah = *(const bf16x8*)&a.hlh[(size_t)b * Hh + kk + quad * 8];
          bf16x8 al = *(const bf16x8*)&a.hll[(size_t)b * Hh + kk + quad * 8];
          acc[mt] = MFMA16(ah, bh, acc[mt]);
          acc[mt] = MFMA16(al, bh, acc[mt]);
          acc[mt] = MFMA16(ah, bl, acc[mt]);
        }
      }
#pragma unroll
      for (int mt = 0; mt < 2; ++mt)
#pragma unroll
        for (int r = 0; r < 4; ++r) red[w][mt * 16 + quad * 4 + r][l16] = acc[mt][r];
      __syncthreads();
#pragma unroll
      for (int i = 0; i < 2; ++i) {
        int idx = tid + i * 256;
        int b = idx >> 4, jl = idx & 15;
        int j = blk * 16 + jl;
        float val =
            red[0][b][jl] + red[1][b][jl] + red[2][b][jl] + red[3][b][jl] + a.zrwe[b * KC + j];
        if (j < Hh) {
          a.z[b * Hh + j] = sigf(val);
        } else {
          int e = j - Hh;
          float rv = sigf(val) * a.we[b * Ee + e];
          bf16 hb = (bf16)rv;
          a.rweh[b * Ee + e] = hb;
          a.rwel[b * Ee + e] = (bf16)(rv - (float)hb);
        }
      }
    }
    gridbar(a.bar, blk);

    // ===== phase C: hh tile = [rwe | h_lstm] @ Wh[jt]^T ; h update =====
    if (blk >= 96 && blk < 160) {
      int j0 = (blk - 96) * 16;
      f32x4 acc[2];
      acc[0] = (f32x4){0.f, 0.f, 0.f, 0.f};
      acc[1] = (f32x4){0.f, 0.f, 0.f, 0.f};
#pragma unroll
      for (int it = 0; it < 12; ++it) {
        int kk = w * 384 + it * 32;
        bf16x8 bh, bl;
        if (kk < Ee) {
          bh = *(const bf16x8*)&a.Whh2[(size_t)(j0 + l16) * KC + kk + quad * 8];
          bl = *(const bf16x8*)&a.Whl2[(size_t)(j0 + l16) * KC + kk + quad * 8];
        } else {
          int eo = (kk - Ee) + quad * 8;
          int d = l16 * 1024 + (eo ^ ((l16 & 7) << 3));
          bh = *(const bf16x8*)&sWx[0][d];
          bl = *(const bf16x8*)&sWx[1][d];
        }
#pragma unroll
        for (int mt = 0; mt < 2; ++mt) {
          int b = mt * 16 + l16;
          bf16x8 ah, al;
          if (kk < Ee) {
            ah = *(const bf16x8*)&a.rweh[(size_t)b * Ee + kk + quad * 8];
            al = *(const bf16x8*)&a.rwel[(size_t)b * Ee + kk + quad * 8];
          } else {
            ah = *(const bf16x8*)&a.hlh[(size_t)b * Hh + (kk - Ee) + quad * 8];
            al = *(const bf16x8*)&a.hll[(size_t)b * Hh + (kk - Ee) + quad * 8];
          }
          acc[mt] = MFMA16(ah, bh, acc[mt]);
          acc[mt] = MFMA16(al, bh, acc[mt]);
          acc[mt] = MFMA16(ah, bl, acc[mt]);
        }
      }
#pragma unroll
      for (int mt = 0; mt < 2; ++mt)
#pragma unroll
        for (int r = 0; r < 4; ++r) red[w][mt * 16 + quad * 4 + r][l16] = acc[mt][r];
      __syncthreads();
#pragma unroll
      for (int i = 0; i < 2; ++i) {
        int idx = tid + i * 256;
        int b = idx >> 4, jl = idx & 15;
        int j = j0 + jl;
        float hhv = tanhf(red[0][b][jl] + red[1][b][jl] + red[2][b][jl] + red[3][b][jl] +
                          a.bhb[j]);
        float hlv = a.hl[b * Hh + j];
        float zz = a.z[b * Hh + j];
        float hn = (1.f - zz) * hlv + zz * hhv;
        a.hf[b * Hh + j] = hn;
        bf16 hb = (bf16)hn;
        a.h_h[b * Hh + j] = hb;
        a.h_l[b * Hh + j] = (bf16)(hn - (float)hb);
        a.hs[((size_t)t * Bb + b) * Hh + j] = hb;
      }
    }
    gridbar(a.bar, blk);
  }
}

// ---------------- final projection: out = hs @ Wo.T + bo (128x128 tiles, swizzled LDS) ----

__global__ __launch_bounds__(256) void k_gemm_out(const bf16* __restrict__ hs,
                                                  const float* __restrict__ Wo,
                                                  const float* __restrict__ bo,
                                                  float* __restrict__ out) {
  int id = blockIdx.x;
  int r_ = id & 7, s_ = id >> 3;
  int mi = s_ & 7;
  int ni = (s_ >> 3) * 8 + r_;
  if (ni >= Vv / 128) return;
  int m0 = mi * 128, n0 = ni * 128;

  int tid = threadIdx.x;
  int w = tid >> 6, lane = tid & 63;
  int l16 = lane & 15, quad = lane >> 4;
  int wm = w & 1, wn = w >> 1;
  int swl = ((l16 >> 1) & 3) << 3;  // lane-constant read swizzle ((row>>1)&3)<<3

  __shared__ __align__(16) bf16 A_lds[128 * 32];
  __shared__ __align__(16) bf16 B_lds[128 * 32];

  f32x4 acc[4][4];
#pragma unroll
  for (int i = 0; i < 4; ++i)
#pragma unroll
    for (int j = 0; j < 4; ++j) acc[i][j] = (f32x4){0.f, 0.f, 0.f, 0.f};

  for (int kt = 0; kt < 32; ++kt) {
    int k0 = kt * 32;
#pragma unroll
    for (int i = 0; i < 2; ++i) {
      int cid = tid + i * 256;
      int row = cid >> 2, ch = cid & 3;
      int sw = ((row >> 1) & 3) << 3;
      *(int4*)&A_lds[row * 32 + ((ch * 8) ^ sw)] =
          *(const int4*)&hs[(size_t)(m0 + row) * Hh + k0 + ch * 8];
    }
#pragma unroll
    for (int i = 0; i < 4; ++i) {
      int cid = tid + i * 256;
      int row = cid >> 3, ch = cid & 7;
      int sw = ((row >> 1) & 3) << 3;
      float4 v = *(const float4*)&Wo[(size_t)(n0 + row) * Hh + k0 + ch * 4];
      bf16x4v bv = {(bf16)v.x, (bf16)v.y, (bf16)v.z, (bf16)v.w};
      *(bf16x4v*)&B_lds[row * 32 + ((ch * 4) ^ sw)] = bv;
    }
    __syncthreads();

    bf16x8 af[4], bfr[4];
#pragma unroll
    for (int i = 0; i < 4; ++i)
      af[i] = *(const bf16x8*)&A_lds[(wm * 64 + i * 16 + l16) * 32 + ((quad * 8) ^ swl)];
#pragma unroll
    for (int j = 0; j < 4; ++j)
      bfr[j] = *(const bf16x8*)&B_lds[(wn * 64 + j * 16 + l16) * 32 + ((quad * 8) ^ swl)];
#pragma unroll
    for (int i = 0; i < 4; ++i)
#pragma unroll
      for (int j = 0; j < 4; ++j) acc[i][j] = MFMA16(af[i], bfr[j], acc[i][j]);
    __syncthreads();
  }

#pragma unroll
  for (int i = 0; i < 4; ++i)
#pragma unroll
    for (int j = 0; j < 4; ++j)
#pragma unroll
      for (int r = 0; r < 4; ++r) {
        int m = m0 + wm * 64 + i * 16 + quad * 4 + r;
        int n = n0 + wn * 64 + j * 16 + l16;
        out[(size_t)m * Vv + n] = acc[i][j][r] + bo[n];
      }
}

__global__ void k_copy_hc(const float* __restrict__ h_f32, const float* __restrict__ c_f32,
                          float* __restrict__ out) {
  int i = blockIdx.x * 256 + threadIdx.x;  // 0..32767
  size_t base = (size_t)Ss * Bb * Vv;
  out[base + i] = h_f32[i];
  out[base + Bb * Hh + i] = c_f32[i];
}

// ---------------- host ----------------

extern "C" void kernel_launch(void* const* d_in, const int* in_sizes, int n_in,
                              void* d_out, int out_size, void* d_ws, size_t ws_size,
                              hipStream_t stream) {
  const int* word = (const int*)d_in[0];
  const int* seq = (const int*)d_in[1];
  const float* emb = (const float*)d_in[2];
  const float* Wl = (const float*)d_in[3];
  const float* bl = (const float*)d_in[4];
  const float* Wih = (const float*)d_in[5];
  const float* Whh = (const float*)d_in[6];
  const float* bih = (const float*)d_in[7];
  const float* bhh = (const float*)d_in[8];
  const float* Wz = (const float*)d_in[9];
  const float* bz = (const float*)d_in[10];
  const float* Wr = (const float*)d_in[11];
  const float* br = (const float*)d_in[12];
  const float* Wh = (const float*)d_in[13];
  const float* bh = (const float*)d_in[14];
  const float* Wo = (const float*)d_in[15];
  const float* bo = (const float*)d_in[16];
  float* out = (float*)d_out;

  char* p = (char*)d_ws;
  auto alloc = [&](size_t bytes) -> char* {
    char* q = p;
    p += (bytes + 255) & ~(size_t)255;
    return q;
  };
  unsigned* bar = (unsigned*)alloc(1024);
  float* we_f32 = (float*)alloc(Bb * Ee * 4);
  float* zrwe = (float*)alloc(Bb * KC * 4);
  float* c_f32 = (float*)alloc(Bb * Hh * 4);
  float* hl_f32 = (float*)alloc(Bb * Hh * 4);
  float* z_f32 = (float*)alloc(Bb * Hh * 4);
  float* hf_f32 = (float*)alloc(Bb * Hh * 4);
  bf16* h_h = (bf16*)alloc(Bb * Hh * 2);
  bf16* h_l = (bf16*)alloc(Bb * Hh * 2);
  bf16* hlh = (bf16*)alloc(Bb * Hh * 2);
  bf16* hll = (bf16*)alloc(Bb * Hh * 2);
  bf16* rweh = (bf16*)alloc(Bb * Ee * 2);
  bf16* rwel = (bf16*)alloc(Bb * Ee * 2);
  bf16* se_h = (bf16*)alloc((size_t)Ss * Bb * Ee * 2);
  bf16* se_l = (bf16*)alloc((size_t)Ss * Bb * Ee * 2);
  bf16* hs_b = (bf16*)alloc((size_t)Ss * Bb * Hh * 2);
  bf16* Wgh = (bf16*)alloc((size_t)4 * Hh * KC * 2);
  bf16* Wgl = (bf16*)alloc((size_t)4 * Hh * KC * 2);
  bf16* W2h = (bf16*)alloc((size_t)KC * Hh * 2);
  bf16* W2l = (bf16*)alloc((size_t)KC * Hh * 2);
  bf16* Whh2 = (bf16*)alloc((size_t)Hh * KC * 2);
  bf16* Whl2 = (bf16*)alloc((size_t)Hh * KC * 2);
  float* bg = (float*)alloc((size_t)4 * Hh * 4);

  dim3 blk(256);
  hipMemsetAsync(bar, 0, 1024, stream);
  k_conv_gates<<<dim3(6, 4096), blk, 0, stream>>>(Wih, Whh, bih, bhh, Wgh, Wgl, bg);
  k_conv_zr2<<<dim3(4, 1536), blk, 0, stream>>>(Wz, Wr, W2h, W2l);
  k_conv_wh<<<dim3(6, 1024), blk, 0, stream>>>(Wh, Whh2, Whl2);
  k_gather_we<<<dim3(2, 32), blk, 0, stream>>>(word, emb, we_f32);
  k_gather_se<<<dim3(2, Ss * Bb), blk, 0, stream>>>(seq, emb, se_h, se_l);
  k_init_h0<<<8192, blk, 0, stream>>>(we_f32, Wl, bl, c_f32, h_h, h_l);
  k_zrwe<<<24, blk, 0, stream>>>(we_f32, Wz, Wr, bz, br, zrwe);

  RecurArgs ra;
  ra.Wgh = Wgh; ra.Wgl = Wgl;
  ra.W2h = W2h; ra.W2l = W2l;
  ra.Whh2 = Whh2; ra.Whl2 = Whl2;
  ra.seh = se_h; ra.sel = se_l;
  ra.bg = bg; ra.bhb = bh; ra.zrwe = zrwe; ra.we = we_f32;
  ra.h_h = h_h; ra.h_l = h_l;
  ra.c = c_f32; ra.hl = hl_f32; ra.z = z_f32; ra.hf = hf_f32;
  ra.hlh = hlh; ra.hll = hll;
  ra.rweh = rweh; ra.rwel = rwel;
  ra.hs = hs_b;
  ra.bar = bar;
  k_recur<<<256, blk, 0, stream>>>(ra);

  k_gemm_out<<<2048, blk, 0, stream>>>(hs_b, Wo, bo, out);
  k_copy_hc<<<128, blk, 0, stream>>>(hf_f32, c_f32, out);
}

// Round 2
// 1852.758 us; speedup vs baseline: 2.9618x; 2.9618x over previous
//
#include <hip/hip_runtime.h>

// DefSeq R3: persistent recurrence with fence-free coherence.
// State crosses blocks via sc0/sc1 write-through atomics (SYSTEM-scope relaxed);
// barrier = flat monotonic counter with AGENT-scope relaxed RMWs. No cache-wide
// invalidates/writebacks anywhere -> weights stay L2-resident across all steps.

typedef __bf16 bf16;
typedef __bf16 bf16x8 __attribute__((ext_vector_type(8)));
typedef __bf16 bf16x4v __attribute__((ext_vector_type(4)));
typedef float f32x4 __attribute__((ext_vector_type(4)));
typedef unsigned long long u64;
typedef unsigned int u32;

#define Vv 32000
#define Ee 512
#define Hh 1024
#define Ss 32
#define Bb 32
#define KC 1536

#define MFMA16(a, b, c) __builtin_amdgcn_mfma_f32_16x16x32_bf16(a, b, c, 0, 0, 0)

static __device__ __forceinline__ float sigf(float x) { return 1.0f / (1.0f + __expf(-x)); }

// ---- coherent (write-through, cache-bypassing) state access helpers ----
static __device__ __forceinline__ u64 cload_u64(const void* p) {
  return __hip_atomic_load((const u64*)p, __ATOMIC_RELAXED, __HIP_MEMORY_SCOPE_SYSTEM);
}
static __device__ __forceinline__ void cstore_u64(void* p, u64 v) {
  __hip_atomic_store((u64*)p, v, __ATOMIC_RELAXED, __HIP_MEMORY_SCOPE_SYSTEM);
}
static __device__ __forceinline__ void cstore_u32(void* p, u32 v) {
  __hip_atomic_store((u32*)p, v, __ATOMIC_RELAXED, __HIP_MEMORY_SCOPE_SYSTEM);
}
static __device__ __forceinline__ bf16x8 cload_bf8(const bf16* p) {
  union { u64 w[2]; bf16x8 v; } u;
  u.w[0] = cload_u64(p);
  u.w[1] = cload_u64(p + 4);
  return u.v;
}
union F2U64 { float f[2]; u64 u; };
union B2U32 { bf16 h[2]; u32 u; };

// ---------------- weight conversion ----------------

// Permuted gate weights: row g = 4*k + s  <->  source row s*1024 + k (s = i,f,g,o).
__global__ void k_conv_gates(const float* __restrict__ Wih, const float* __restrict__ Whh,
                             const float* __restrict__ bih, const float* __restrict__ bhh,
                             bf16* __restrict__ Wgh, bf16* __restrict__ Wgl,
                             float* __restrict__ bg) {
  int g = blockIdx.y;
  int col = blockIdx.x * 256 + threadIdx.x;
  int k = g >> 2, s = g & 3;
  int src = s * Hh + k;
  float v = (col < Ee) ? Wih[(size_t)src * Ee + col] : Whh[(size_t)src * Hh + (col - Ee)];
  bf16 h = (bf16)v;
  Wgh[(size_t)g * KC + col] = h;
  Wgl[(size_t)g * KC + col] = (bf16)(v - (float)h);
  if (col == 0) bg[g] = bih[src] + bhh[src];
}

// [Wz;Wr] rows, cols [512,1536) only (h-part)
__global__ void k_conv_zr2(const float* __restrict__ Wz, const float* __restrict__ Wr,
                           bf16* __restrict__ W2h, bf16* __restrict__ W2l) {
  int j = blockIdx.y;
  int col = blockIdx.x * 256 + threadIdx.x;
  float v = (j < Hh) ? Wz[(size_t)j * KC + Ee + col] : Wr[(size_t)(j - Hh) * KC + Ee + col];
  bf16 h = (bf16)v;
  W2h[(size_t)j * Hh + col] = h;
  W2l[(size_t)j * Hh + col] = (bf16)(v - (float)h);
}

__global__ void k_conv_wh(const float* __restrict__ A, bf16* __restrict__ hi,
                          bf16* __restrict__ lo) {
  int j = blockIdx.y;
  int k = blockIdx.x * 256 + threadIdx.x;
  float v = A[(size_t)j * KC + k];
  bf16 h = (bf16)v;
  hi[(size_t)j * KC + k] = h;
  lo[(size_t)j * KC + k] = (bf16)(v - (float)h);
}

// ---------------- gathers / init ----------------

__global__ void k_gather_we(const int* __restrict__ word, const float* __restrict__ emb,
                            float* __restrict__ we) {
  int b = blockIdx.y;
  int e = blockIdx.x * 256 + threadIdx.x;
  we[b * Ee + e] = emb[(size_t)word[b] * Ee + e];
}

__global__ void k_gather_se(const int* __restrict__ seq, const float* __restrict__ emb,
                            bf16* __restrict__ se_h, bf16* __restrict__ se_l) {
  int tb = blockIdx.y;
  int e = blockIdx.x * 256 + threadIdx.x;
  float v = emb[(size_t)seq[tb] * Ee + e];
  bf16 h = (bf16)v;
  se_h[(size_t)tb * Ee + e] = h;
  se_l[(size_t)tb * Ee + e] = (bf16)(v - (float)h);
}

__global__ void k_init_h0(const float* __restrict__ we, const float* __restrict__ Wl,
                          const float* __restrict__ bl, float* __restrict__ c,
                          bf16* __restrict__ h_h, bf16* __restrict__ h_l) {
  int o = blockIdx.x * 4 + (threadIdx.x >> 6);
  int lane = threadIdx.x & 63;
  int b = o >> 10, n = o & 1023;
  const float* wr = we + b * Ee;
  const float* wl = Wl + (size_t)n * Ee;
  int e0 = lane * 8;
  float4 a0 = *(const float4*)(wr + e0);
  float4 a1 = *(const float4*)(wr + e0 + 4);
  float4 b0 = *(const float4*)(wl + e0);
  float4 b1 = *(const float4*)(wl + e0 + 4);
  float s = a0.x * b0.x + a0.y * b0.y + a0.z * b0.z + a0.w * b0.w +
            a1.x * b1.x + a1.y * b1.y + a1.z * b1.z + a1.w * b1.w;
  for (int off = 32; off; off >>= 1) s += __shfl_down(s, off);
  if (lane == 0) {
    s += bl[n];
    c[o] = s;
    bf16 h = (bf16)s;
    h_h[o] = h;
    h_l[o] = (bf16)(s - (float)h);
  }
}

// zrwe[b][j] = we . [Wz;Wr][j][0:512] + (bz|br)[j]
__global__ __launch_bounds__(256) void k_zrwe(const float* __restrict__ we,
                                              const float* __restrict__ Wz,
                                              const float* __restrict__ Wr,
                                              const float* __restrict__ bz,
                                              const float* __restrict__ br,
                                              float* __restrict__ zrwe) {
  int tid = threadIdx.x;
  int w = tid >> 6, lane = tid & 63, l16 = lane & 15, quad = lane >> 4;
  int j0 = (blockIdx.x * 4 + w) * 16;
  int j = j0 + l16;
  const float* wrow = (j < Hh) ? (Wz + (size_t)j * KC) : (Wr + (size_t)(j - Hh) * KC);
  f32x4 acc[2];
  acc[0] = (f32x4){0.f, 0.f, 0.f, 0.f};
  acc[1] = (f32x4){0.f, 0.f, 0.f, 0.f};
  for (int kk = 0; kk < Ee; kk += 32) {
    bf16x8 bh, bl;
#pragma unroll
    for (int i = 0; i < 8; ++i) {
      float v = wrow[kk + quad * 8 + i];
      bf16 hv = (bf16)v;
      bh[i] = hv;
      bl[i] = (bf16)(v - (float)hv);
    }
#pragma unroll
    for (int mt = 0; mt < 2; ++mt) {
      bf16x8 ah, al;
      const float* arow = we + (size_t)(mt * 16 + l16) * Ee + kk + quad * 8;
#pragma unroll
      for (int i = 0; i < 8; ++i) {
        float v = arow[i];
        bf16 hv = (bf16)v;
        ah[i] = hv;
        al[i] = (bf16)(v - (float)hv);
      }
      acc[mt] = MFMA16(ah, bh, acc[mt]);
      acc[mt] = MFMA16(al, bh, acc[mt]);
      acc[mt] = MFMA16(ah, bl, acc[mt]);
    }
  }
  float bias = (j < Hh) ? bz[j] : br[j - Hh];
#pragma unroll
  for (int mt = 0; mt < 2; ++mt)
#pragma unroll
    for (int r = 0; r < 4; ++r) {
      int b = mt * 16 + quad * 4 + r;
      zrwe[b * KC + j] = acc[mt][r] + bias;
    }
}

// ---------------- persistent recurrence ----------------

struct RecurArgs {
  const bf16 *Wgh, *Wgl;
  const bf16 *W2h, *W2l;
  const bf16 *Whh2, *Whl2;
  const bf16 *seh, *sel;
  const float *bg;
  const float *bhb;
  const float *zrwe;
  const float *we;
  bf16 *h_h, *h_l;
  float *c, *hl, *z, *hf;
  bf16 *hlh, *hll;
  bf16 *rweh, *rwel;
  bf16 *hs;
  unsigned *bar;
};

// flat monotonic grid barrier, n = 1,2,3,... ; bar[0]=arrivals, bar[64]=generation.
// No fences: producers drain vmcnt before arriving; all cross-block data uses
// write-through (sc0 sc1) accesses, so visibility is established at the LLC.
static __device__ __forceinline__ void gridbar(unsigned* bar, unsigned n) {
  asm volatile("s_waitcnt vmcnt(0)" ::: "memory");
  __syncthreads();
  if (threadIdx.x == 0) {
    unsigned v = __hip_atomic_fetch_add(bar, 1u, __ATOMIC_RELAXED, __HIP_MEMORY_SCOPE_AGENT);
    if (v == n * 256u - 1u) {
      __hip_atomic_store(bar + 64, n, __ATOMIC_RELAXED, __HIP_MEMORY_SCOPE_AGENT);
    } else {
      while ((int)(__hip_atomic_fetch_add(bar + 64, 0u, __ATOMIC_RELAXED,
                                          __HIP_MEMORY_SCOPE_AGENT) -
                   n) < 0)
        __builtin_amdgcn_s_sleep(4);
    }
  }
  __syncthreads();
}

// grid = 256 blocks x 512 threads (8 waves). LDS 145.4KB -> 1 block/CU.
__global__ __launch_bounds__(512) void k_recur(RecurArgs a) {
  __shared__ __align__(16) bf16 sWa[2][16 * 1024];  // gates: Wg cols [512,1536)
  __shared__ __align__(16) bf16 sWx[2][16 * 1024];  // zr h-part / Wh cols [512,1536)
  __shared__ float red[8][32][17];

  int blk = blockIdx.x, tid = threadIdx.x;
  int w = tid >> 6, lane = tid & 63, l16 = lane & 15, quad = lane >> 4;

  // stage persistent weight slices into LDS, XOR-swizzled
  for (int i = tid; i < 2048; i += 512) {
    int row = i >> 7, ch = i & 127, e = ch * 8;
    int d = row * 1024 + (e ^ ((row & 7) << 3));
    *(bf16x8*)&sWa[0][d] = *(const bf16x8*)&a.Wgh[(size_t)(blk * 16 + row) * KC + Ee + e];
    *(bf16x8*)&sWa[1][d] = *(const bf16x8*)&a.Wgl[(size_t)(blk * 16 + row) * KC + Ee + e];
    if (blk < 96) {
      *(bf16x8*)&sWx[0][d] = *(const bf16x8*)&a.W2h[(size_t)(blk * 16 + row) * Hh + e];
      *(bf16x8*)&sWx[1][d] = *(const bf16x8*)&a.W2l[(size_t)(blk * 16 + row) * Hh + e];
    } else if (blk < 160) {
      *(bf16x8*)&sWx[0][d] =
          *(const bf16x8*)&a.Whh2[(size_t)((blk - 96) * 16 + row) * KC + Ee + e];
      *(bf16x8*)&sWx[1][d] =
          *(const bf16x8*)&a.Whl2[(size_t)((blk - 96) * 16 + row) * KC + Ee + e];
    }
  }
  __syncthreads();

  unsigned bcnt = 0;

  for (int t = 0; t < Ss; ++t) {
    // ===== phase A: gates tile = [se_t | h] @ Wg[blk]^T, then LSTM pointwise =====
    {
      f32x4 acc[2];
      acc[0] = (f32x4){0.f, 0.f, 0.f, 0.f};
      acc[1] = (f32x4){0.f, 0.f, 0.f, 0.f};
#pragma unroll
      for (int it = 0; it < 6; ++it) {
        int kk = w * 192 + it * 32;
        bf16x8 bh, bl;
        if (kk < Ee) {
          bh = *(const bf16x8*)&a.Wgh[(size_t)(blk * 16 + l16) * KC + kk + quad * 8];
          bl = *(const bf16x8*)&a.Wgl[(size_t)(blk * 16 + l16) * KC + kk + quad * 8];
        } else {
          int eo = (kk - Ee) + quad * 8;
          int d = l16 * 1024 + (eo ^ ((l16 & 7) << 3));
          bh = *(const bf16x8*)&sWa[0][d];
          bl = *(const bf16x8*)&sWa[1][d];
        }
#pragma unroll
        for (int mt = 0; mt < 2; ++mt) {
          int bb = mt * 16 + l16;
          bf16x8 ah, al;
          if (kk < Ee) {
            ah = *(const bf16x8*)&a.seh[(size_t)(t * Bb + bb) * Ee + kk + quad * 8];
            al = *(const bf16x8*)&a.sel[(size_t)(t * Bb + bb) * Ee + kk + quad * 8];
          } else {
            ah = cload_bf8(&a.h_h[(size_t)bb * Hh + (kk - Ee) + quad * 8]);
            al = cload_bf8(&a.h_l[(size_t)bb * Hh + (kk - Ee) + quad * 8]);
          }
          acc[mt] = MFMA16(ah, bh, acc[mt]);
          acc[mt] = MFMA16(al, bh, acc[mt]);
          acc[mt] = MFMA16(ah, bl, acc[mt]);
        }
      }
#pragma unroll
      for (int mt = 0; mt < 2; ++mt)
#pragma unroll
        for (int r = 0; r < 4; ++r) red[w][mt * 16 + quad * 4 + r][l16] = acc[mt][r];
    }
    __syncthreads();
    if (tid < 64) {
      int bb = tid >> 1, kl0 = (tid & 1) * 2;
      B2U32 ph, pl;
      F2U64 phl;
#pragma unroll
      for (int u2 = 0; u2 < 2; ++u2) {
        int kl = kl0 + u2;
        float g4[4];
#pragma unroll
        for (int s = 0; s < 4; ++s) {
          int jl = kl * 4 + s;
          float sum = a.bg[blk * 16 + jl];
#pragma unroll
          for (int w2 = 0; w2 < 8; ++w2) sum += red[w2][bb][jl];
          g4[s] = sum;
        }
        int idx = bb * Hh + blk * 4 + kl;
        float cn = sigf(g4[1]) * a.c[idx] + sigf(g4[0]) * tanhf(g4[2]);
        float hvv = sigf(g4[3]) * tanhf(cn);
        a.c[idx] = cn;  // block-private across steps: normal access OK
        phl.f[u2] = hvv;
        bf16 hb = (bf16)hvv;
        ph.h[u2] = hb;
        pl.h[u2] = (bf16)(hvv - (float)hb);
      }
      int base = bb * Hh + blk * 4 + kl0;
      cstore_u64(&a.hl[base], phl.u);
      cstore_u32(&a.hlh[base], ph.u);
      cstore_u32(&a.hll[base], pl.u);
    }
    gridbar(a.bar, ++bcnt);

    // ===== phase B: [z;r] tile = zrwe + h_lstm @ W2[blk]^T ; r*we -> rwe =====
    if (blk < 96) {
      f32x4 acc[2];
      acc[0] = (f32x4){0.f, 0.f, 0.f, 0.f};
      acc[1] = (f32x4){0.f, 0.f, 0.f, 0.f};
#pragma unroll
      for (int it = 0; it < 4; ++it) {
        int kk = w * 128 + it * 32;
        int eo = kk + quad * 8;
        int d = l16 * 1024 + (eo ^ ((l16 & 7) << 3));
        bf16x8 bh = *(const bf16x8*)&sWx[0][d];
        bf16x8 bl = *(const bf16x8*)&sWx[1][d];
#pragma unroll
        for (int mt = 0; mt < 2; ++mt) {
          int bb = mt * 16 + l16;
          bf16x8 ah = cload_bf8(&a.hlh[(size_t)bb * Hh + kk + quad * 8]);
          bf16x8 al = cload_bf8(&a.hll[(size_t)bb * Hh + kk + quad * 8]);
          acc[mt] = MFMA16(ah, bh, acc[mt]);
          acc[mt] = MFMA16(al, bh, acc[mt]);
          acc[mt] = MFMA16(ah, bl, acc[mt]);
        }
      }
#pragma unroll
      for (int mt = 0; mt < 2; ++mt)
#pragma unroll
        for (int r = 0; r < 4; ++r) red[w][mt * 16 + quad * 4 + r][l16] = acc[mt][r];
      __syncthreads();
      if (tid < 256) {
        int bb = tid >> 3, jl0 = (tid & 7) * 2;
        float v[2];
#pragma unroll
        for (int u2 = 0; u2 < 2; ++u2) {
          int jl = jl0 + u2;
          int j = blk * 16 + jl;
          float s = a.zrwe[bb * KC + j];
#pragma unroll
          for (int w2 = 0; w2 < 8; ++w2) s += red[w2][bb][jl];
          v[u2] = s;
        }
        int j = blk * 16 + jl0;
        if (blk < 64) {
          F2U64 pz;
          pz.f[0] = sigf(v[0]);
          pz.f[1] = sigf(v[1]);
          cstore_u64(&a.z[bb * Hh + j], pz.u);
        } else {
          int e = j - Hh;
          B2U32 ph, pl;
#pragma unroll
          for (int u2 = 0; u2 < 2; ++u2) {
            float rv = sigf(v[u2]) * a.we[bb * Ee + e + u2];
            bf16 hb = (bf16)rv;
            ph.h[u2] = hb;
            pl.h[u2] = (bf16)(rv - (float)hb);
          }
          cstore_u32(&a.rweh[bb * Ee + e], ph.u);
          cstore_u32(&a.rwel[bb * Ee + e], pl.u);
        }
      }
    }
    gridbar(a.bar, ++bcnt);

    // ===== phase C: hh tile = [rwe | h_lstm] @ Wh[jt]^T ; h update =====
    if (blk >= 96 && blk < 160) {
      int j0 = (blk - 96) * 16;
      f32x4 acc[2];
      acc[0] = (f32x4){0.f, 0.f, 0.f, 0.f};
      acc[1] = (f32x4){0.f, 0.f, 0.f, 0.f};
#pragma unroll
      for (int it = 0; it < 6; ++it) {
        int kk = w * 192 + it * 32;
        bf16x8 bh, bl;
        if (kk < Ee) {
          bh = *(const bf16x8*)&a.Whh2[(size_t)(j0 + l16) * KC + kk + quad * 8];
          bl = *(const bf16x8*)&a.Whl2[(size_t)(j0 + l16) * KC + kk + quad * 8];
        } else {
          int eo = (kk - Ee) + quad * 8;
          int d = l16 * 1024 + (eo ^ ((l16 & 7) << 3));
          bh = *(const bf16x8*)&sWx[0][d];
          bl = *(const bf16x8*)&sWx[1][d];
        }
#pragma unroll
        for (int mt = 0; mt < 2; ++mt) {
          int bb = mt * 16 + l16;
          bf16x8 ah, al;
          if (kk < Ee) {
            ah = cload_bf8(&a.rweh[(size_t)bb * Ee + kk + quad * 8]);
            al = cload_bf8(&a.rwel[(size_t)bb * Ee + kk + quad * 8]);
          } else {
            ah = cload_bf8(&a.hlh[(size_t)bb * Hh + (kk - Ee) + quad * 8]);
            al = cload_bf8(&a.hll[(size_t)bb * Hh + (kk - Ee) + quad * 8]);
          }
          acc[mt] = MFMA16(ah, bh, acc[mt]);
          acc[mt] = MFMA16(al, bh, acc[mt]);
          acc[mt] = MFMA16(ah, bl, acc[mt]);
        }
      }
#pragma unroll
      for (int mt = 0; mt < 2; ++mt)
#pragma unroll
        for (int r = 0; r < 4; ++r) red[w][mt * 16 + quad * 4 + r][l16] = acc[mt][r];
      __syncthreads();
      if (tid < 256) {
        int bb = tid >> 3, jl0 = (tid & 7) * 2;
        int j = j0 + jl0;
        F2U64 hlp, zp;
        hlp.u = cload_u64(&a.hl[bb * Hh + j]);
        zp.u = cload_u64(&a.z[bb * Hh + j]);
        B2U32 ph, pl, phs;
        float hf2[2];
#pragma unroll
        for (int u2 = 0; u2 < 2; ++u2) {
          int jl = jl0 + u2;
          float s = a.bhb[j + u2];
#pragma unroll
          for (int w2 = 0; w2 < 8; ++w2) s += red[w2][bb][jl];
          float hhv = tanhf(s);
          float hn = (1.f - zp.f[u2]) * hlp.f[u2] + zp.f[u2] * hhv;
          hf2[u2] = hn;
          bf16 hb = (bf16)hn;
          ph.h[u2] = hb;
          pl.h[u2] = (bf16)(hn - (float)hb);
          phs.h[u2] = hb;
        }
        a.hf[bb * Hh + j] = hf2[0];      // consumed by next kernel: normal OK
        a.hf[bb * Hh + j + 1] = hf2[1];
        cstore_u32(&a.h_h[bb * Hh + j], ph.u);
        cstore_u32(&a.h_l[bb * Hh + j], pl.u);
        *(u32*)&a.hs[((size_t)t * Bb + bb) * Hh + j] = phs.u;  // next kernel: normal OK
      }
    }
    gridbar(a.bar, ++bcnt);
  }
}

// ---------------- final projection: out = hs @ Wo.T + bo (128x128 tiles, swizzled LDS) ----

__global__ __launch_bounds__(256) void k_gemm_out(const bf16* __restrict__ hs,
                                                  const float* __restrict__ Wo,
                                                  const float* __restrict__ bo,
                                                  float* __restrict__ out) {
  int id = blockIdx.x;
  int r_ = id & 7, s_ = id >> 3;
  int mi = s_ & 7;
  int ni = (s_ >> 3) * 8 + r_;
  if (ni >= Vv / 128) return;
  int m0 = mi * 128, n0 = ni * 128;

  int tid = threadIdx.x;
  int w = tid >> 6, lane = tid & 63;
  int l16 = lane & 15, quad = lane >> 4;
  int wm = w & 1, wn = w >> 1;
  int swl = ((l16 >> 1) & 3) << 3;

  __shared__ __align__(16) bf16 A_lds[128 * 32];
  __shared__ __align__(16) bf16 B_lds[128 * 32];

  f32x4 acc[4][4];
#pragma unroll
  for (int i = 0; i < 4; ++i)
#pragma unroll
    for (int j = 0; j < 4; ++j) acc[i][j] = (f32x4){0.f, 0.f, 0.f, 0.f};

  for (int kt = 0; kt < 32; ++kt) {
    int k0 = kt * 32;
#pragma unroll
    for (int i = 0; i < 2; ++i) {
      int cid = tid + i * 256;
      int row = cid >> 2, ch = cid & 3;
      int sw = ((row >> 1) & 3) << 3;
      *(int4*)&A_lds[row * 32 + ((ch * 8) ^ sw)] =
          *(const int4*)&hs[(size_t)(m0 + row) * Hh + k0 + ch * 8];
    }
#pragma unroll
    for (int i = 0; i < 4; ++i) {
      int cid = tid + i * 256;
      int row = cid >> 3, ch = cid & 7;
      int sw = ((row >> 1) & 3) << 3;
      float4 v = *(const float4*)&Wo[(size_t)(n0 + row) * Hh + k0 + ch * 4];
      bf16x4v bv = {(bf16)v.x, (bf16)v.y, (bf16)v.z, (bf16)v.w};
      *(bf16x4v*)&B_lds[row * 32 + ((ch * 4) ^ sw)] = bv;
    }
    __syncthreads();

    bf16x8 af[4], bfr[4];
#pragma unroll
    for (int i = 0; i < 4; ++i)
      af[i] = *(const bf16x8*)&A_lds[(wm * 64 + i * 16 + l16) * 32 + ((quad * 8) ^ swl)];
#pragma unroll
    for (int j = 0; j < 4; ++j)
      bfr[j] = *(const bf16x8*)&B_lds[(wn * 64 + j * 16 + l16) * 32 + ((quad * 8) ^ swl)];
#pragma unroll
    for (int i = 0; i < 4; ++i)
#pragma unroll
      for (int j = 0; j < 4; ++j) acc[i][j] = MFMA16(af[i], bfr[j], acc[i][j]);
    __syncthreads();
  }

#pragma unroll
  for (int i = 0; i < 4; ++i)
#pragma unroll
    for (int j = 0; j < 4; ++j)
#pragma unroll
      for (int r = 0; r < 4; ++r) {
        int m = m0 + wm * 64 + i * 16 + quad * 4 + r;
        int n = n0 + wn * 64 + j * 16 + l16;
        out[(size_t)m * Vv + n] = acc[i][j][r] + bo[n];
      }
}

__global__ void k_copy_hc(const float* __restrict__ h_f32, const float* __restrict__ c_f32,
                          float* __restrict__ out) {
  int i = blockIdx.x * 256 + threadIdx.x;
  size_t base = (size_t)Ss * Bb * Vv;
  out[base + i] = h_f32[i];
  out[base + Bb * Hh + i] = c_f32[i];
}

// ---------------- host ----------------

extern "C" void kernel_launch(void* const* d_in, const int* in_sizes, int n_in,
                              void* d_out, int out_size, void* d_ws, size_t ws_size,
                              hipStream_t stream) {
  const int* word = (const int*)d_in[0];
  const int* seq = (const int*)d_in[1];
  const float* emb = (const float*)d_in[2];
  const float* Wl = (const float*)d_in[3];
  const float* bl = (const float*)d_in[4];
  const float* Wih = (const float*)d_in[5];
  const float* Whh = (const float*)d_in[6];
  const float* bih = (const float*)d_in[7];
  const float* bhh = (const float*)d_in[8];
  const float* Wz = (const float*)d_in[9];
  const float* bz = (const float*)d_in[10];
  const float* Wr = (const float*)d_in[11];
  const float* br = (const float*)d_in[12];
  const float* Wh = (const float*)d_in[13];
  const float* bh = (const float*)d_in[14];
  const float* Wo = (const float*)d_in[15];
  const float* bo = (const float*)d_in[16];
  float* out = (float*)d_out;

  char* p = (char*)d_ws;
  auto alloc = [&](size_t bytes) -> char* {
    char* q = p;
    p += (bytes + 255) & ~(size_t)255;
    return q;
  };
  unsigned* bar = (unsigned*)alloc(1024);
  float* we_f32 = (float*)alloc(Bb * Ee * 4);
  float* zrwe = (float*)alloc(Bb * KC * 4);
  float* c_f32 = (float*)alloc(Bb * Hh * 4);
  float* hl_f32 = (float*)alloc(Bb * Hh * 4);
  float* z_f32 = (float*)alloc(Bb * Hh * 4);
  float* hf_f32 = (float*)alloc(Bb * Hh * 4);
  bf16* h_h = (bf16*)alloc(Bb * Hh * 2);
  bf16* h_l = (bf16*)alloc(Bb * Hh * 2);
  bf16* hlh = (bf16*)alloc(Bb * Hh * 2);
  bf16* hll = (bf16*)alloc(Bb * Hh * 2);
  bf16* rweh = (bf16*)alloc(Bb * Ee * 2);
  bf16* rwel = (bf16*)alloc(Bb * Ee * 2);
  bf16* se_h = (bf16*)alloc((size_t)Ss * Bb * Ee * 2);
  bf16* se_l = (bf16*)alloc((size_t)Ss * Bb * Ee * 2);
  bf16* hs_b = (bf16*)alloc((size_t)Ss * Bb * Hh * 2);
  bf16* Wgh = (bf16*)alloc((size_t)4 * Hh * KC * 2);
  bf16* Wgl = (bf16*)alloc((size_t)4 * Hh * KC * 2);
  bf16* W2h = (bf16*)alloc((size_t)KC * Hh * 2);
  bf16* W2l = (bf16*)alloc((size_t)KC * Hh * 2);
  bf16* Whh2 = (bf16*)alloc((size_t)Hh * KC * 2);
  bf16* Whl2 = (bf16*)alloc((size_t)Hh * KC * 2);
  float* bg = (float*)alloc((size_t)4 * Hh * 4);

  dim3 blk(256);
  hipMemsetAsync(bar, 0, 1024, stream);
  k_conv_gates<<<dim3(6, 4096), blk, 0, stream>>>(Wih, Whh, bih, bhh, Wgh, Wgl, bg);
  k_conv_zr2<<<dim3(4, 1536), blk, 0, stream>>>(Wz, Wr, W2h, W2l);
  k_conv_wh<<<dim3(6, 1024), blk, 0, stream>>>(Wh, Whh2, Whl2);
  k_gather_we<<<dim3(2, 32), blk, 0, stream>>>(word, emb, we_f32);
  k_gather_se<<<dim3(2, Ss * Bb), blk, 0, stream>>>(seq, emb, se_h, se_l);
  k_init_h0<<<8192, blk, 0, stream>>>(we_f32, Wl, bl, c_f32, h_h, h_l);
  k_zrwe<<<24, blk, 0, stream>>>(we_f32, Wz, Wr, bz, br, zrwe);

  RecurArgs ra;
  ra.Wgh = Wgh; ra.Wgl = Wgl;
  ra.W2h = W2h; ra.W2l = W2l;
  ra.Whh2 = Whh2; ra.Whl2 = Whl2;
  ra.seh = se_h; ra.sel = se_l;
  ra.bg = bg; ra.bhb = bh; ra.zrwe = zrwe; ra.we = we_f32;
  ra.h_h = h_h; ra.h_l = h_l;
  ra.c = c_f32; ra.hl = hl_f32; ra.z = z_f32; ra.hf = hf_f32;
  ra.hlh = hlh; ra.hll = hll;
  ra.rweh = rweh; ra.rwel = rwel;
  ra.hs = hs_b;
  ra.bar = bar;
  k_recur<<<256, dim3(512), 0, stream>>>(ra);

  k_gemm_out<<<2048, blk, 0, stream>>>(hs_b, Wo, bo, out);
  k_copy_hc<<<128, blk, 0, stream>>>(hf_f32, c_f32, out);
}

// Round 3
// 1798.093 us; speedup vs baseline: 3.0518x; 1.0304x over previous
//
#include <hip/hip_runtime.h>

// DefSeq R4: persistent recurrence; barrier v3 = tree arrivals (8 lines) +
// LOAD-based generation polling (no RMW storm), participant-minimal channels.
// k_gemm_out: double-buffered LDS pipeline (issue-loads -> compute -> write -> 1 barrier).

typedef __bf16 bf16;
typedef __bf16 bf16x8 __attribute__((ext_vector_type(8)));
typedef __bf16 bf16x4v __attribute__((ext_vector_type(4)));
typedef float f32x4 __attribute__((ext_vector_type(4)));
typedef unsigned long long u64;
typedef unsigned int u32;

#define Vv 32000
#define Ee 512
#define Hh 1024
#define Ss 32
#define Bb 32
#define KC 1536

#define MFMA16(a, b, c) __builtin_amdgcn_mfma_f32_16x16x32_bf16(a, b, c, 0, 0, 0)

static __device__ __forceinline__ float sigf(float x) { return 1.0f / (1.0f + __expf(-x)); }

// ---- coherent (write-through, cache-bypassing) state access helpers ----
static __device__ __forceinline__ u64 cload_u64(const void* p) {
  return __hip_atomic_load((const u64*)p, __ATOMIC_RELAXED, __HIP_MEMORY_SCOPE_SYSTEM);
}
static __device__ __forceinline__ void cstore_u64(void* p, u64 v) {
  __hip_atomic_store((u64*)p, v, __ATOMIC_RELAXED, __HIP_MEMORY_SCOPE_SYSTEM);
}
static __device__ __forceinline__ void cstore_u32(void* p, u32 v) {
  __hip_atomic_store((u32*)p, v, __ATOMIC_RELAXED, __HIP_MEMORY_SCOPE_SYSTEM);
}
static __device__ __forceinline__ bf16x8 cload_bf8(const bf16* p) {
  union { u64 w[2]; bf16x8 v; } u;
  u.w[0] = cload_u64(p);
  u.w[1] = cload_u64(p + 4);
  return u.v;
}
union F2U64 { float f[2]; u64 u; };
union B2U32 { bf16 h[2]; u32 u; };

// ---- barrier v3: monotonic tree arrivals + load-polled generation ----
// dword offsets in bar[]: channel A: cnt 0+g*32 (8 grp x 32), root 256, gen 288
//                         channel B: cnt 320+g*32 (6 grp x 16), root 512, gen 544
//                         channel C: cnt 576+g*32 (8 grp x 8),  root 832, gen 864
static __device__ __forceinline__ void bar_arrive(u32* bar, int cntOff, int rootOff, int genOff,
                                                  u32 grpSize, u32 nGrp, int g, u32 t1) {
  __syncthreads();  // drains vmcnt per-thread -> all state stores at LLC
  if (threadIdx.x == 0) {
    u32 v = __hip_atomic_fetch_add(bar + cntOff + g * 32, 1u, __ATOMIC_RELAXED,
                                   __HIP_MEMORY_SCOPE_AGENT);
    if (v == grpSize * t1 - 1u) {
      u32 r = __hip_atomic_fetch_add(bar + rootOff, 1u, __ATOMIC_RELAXED,
                                     __HIP_MEMORY_SCOPE_AGENT);
      if (r == nGrp * t1 - 1u)
        __hip_atomic_store(bar + genOff, t1, __ATOMIC_RELAXED, __HIP_MEMORY_SCOPE_SYSTEM);
    }
  }
}
static __device__ __forceinline__ void bar_wait(u32* bar, int genOff, u32 t1) {
  if (threadIdx.x == 0) {
    while (__hip_atomic_load(bar + genOff, __ATOMIC_RELAXED, __HIP_MEMORY_SCOPE_SYSTEM) < t1)
      __builtin_amdgcn_s_sleep(8);
  }
  __syncthreads();
}

// ---------------- weight conversion ----------------

__global__ void k_conv_gates(const float* __restrict__ Wih, const float* __restrict__ Whh,
                             const float* __restrict__ bih, const float* __restrict__ bhh,
                             bf16* __restrict__ Wgh, bf16* __restrict__ Wgl,
                             float* __restrict__ bg) {
  int g = blockIdx.y;
  int col = blockIdx.x * 256 + threadIdx.x;
  int k = g >> 2, s = g & 3;
  int src = s * Hh + k;
  float v = (col < Ee) ? Wih[(size_t)src * Ee + col] : Whh[(size_t)src * Hh + (col - Ee)];
  bf16 h = (bf16)v;
  Wgh[(size_t)g * KC + col] = h;
  Wgl[(size_t)g * KC + col] = (bf16)(v - (float)h);
  if (col == 0) bg[g] = bih[src] + bhh[src];
}

__global__ void k_conv_zr2(const float* __restrict__ Wz, const float* __restrict__ Wr,
                           bf16* __restrict__ W2h, bf16* __restrict__ W2l) {
  int j = blockIdx.y;
  int col = blockIdx.x * 256 + threadIdx.x;
  float v = (j < Hh) ? Wz[(size_t)j * KC + Ee + col] : Wr[(size_t)(j - Hh) * KC + Ee + col];
  bf16 h = (bf16)v;
  W2h[(size_t)j * Hh + col] = h;
  W2l[(size_t)j * Hh + col] = (bf16)(v - (float)h);
}

__global__ void k_conv_wh(const float* __restrict__ A, bf16* __restrict__ hi,
                          bf16* __restrict__ lo) {
  int j = blockIdx.y;
  int k = blockIdx.x * 256 + threadIdx.x;
  float v = A[(size_t)j * KC + k];
  bf16 h = (bf16)v;
  hi[(size_t)j * KC + k] = h;
  lo[(size_t)j * KC + k] = (bf16)(v - (float)h);
}

// ---------------- gathers / init ----------------

__global__ void k_gather_we(const int* __restrict__ word, const float* __restrict__ emb,
                            float* __restrict__ we) {
  int b = blockIdx.y;
  int e = blockIdx.x * 256 + threadIdx.x;
  we[b * Ee + e] = emb[(size_t)word[b] * Ee + e];
}

__global__ void k_gather_se(const int* __restrict__ seq, const float* __restrict__ emb,
                            bf16* __restrict__ se_h, bf16* __restrict__ se_l) {
  int tb = blockIdx.y;
  int e = blockIdx.x * 256 + threadIdx.x;
  float v = emb[(size_t)seq[tb] * Ee + e];
  bf16 h = (bf16)v;
  se_h[(size_t)tb * Ee + e] = h;
  se_l[(size_t)tb * Ee + e] = (bf16)(v - (float)h);
}

__global__ void k_init_h0(const float* __restrict__ we, const float* __restrict__ Wl,
                          const float* __restrict__ bl, float* __restrict__ c,
                          bf16* __restrict__ h_h, bf16* __restrict__ h_l) {
  int o = blockIdx.x * 4 + (threadIdx.x >> 6);
  int lane = threadIdx.x & 63;
  int b = o >> 10, n = o & 1023;
  const float* wr = we + b * Ee;
  const float* wl = Wl + (size_t)n * Ee;
  int e0 = lane * 8;
  float4 a0 = *(const float4*)(wr + e0);
  float4 a1 = *(const float4*)(wr + e0 + 4);
  float4 b0 = *(const float4*)(wl + e0);
  float4 b1 = *(const float4*)(wl + e0 + 4);
  float s = a0.x * b0.x + a0.y * b0.y + a0.z * b0.z + a0.w * b0.w +
            a1.x * b1.x + a1.y * b1.y + a1.z * b1.z + a1.w * b1.w;
  for (int off = 32; off; off >>= 1) s += __shfl_down(s, off);
  if (lane == 0) {
    s += bl[n];
    c[o] = s;
    bf16 h = (bf16)s;
    h_h[o] = h;
    h_l[o] = (bf16)(s - (float)h);
  }
}

__global__ __launch_bounds__(256) void k_zrwe(const float* __restrict__ we,
                                              const float* __restrict__ Wz,
                                              const float* __restrict__ Wr,
                                              const float* __restrict__ bz,
                                              const float* __restrict__ br,
                                              float* __restrict__ zrwe) {
  int tid = threadIdx.x;
  int w = tid >> 6, lane = tid & 63, l16 = lane & 15, quad = lane >> 4;
  int j0 = (blockIdx.x * 4 + w) * 16;
  int j = j0 + l16;
  const float* wrow = (j < Hh) ? (Wz + (size_t)j * KC) : (Wr + (size_t)(j - Hh) * KC);
  f32x4 acc[2];
  acc[0] = (f32x4){0.f, 0.f, 0.f, 0.f};
  acc[1] = (f32x4){0.f, 0.f, 0.f, 0.f};
  for (int kk = 0; kk < Ee; kk += 32) {
    bf16x8 bh, bl;
#pragma unroll
    for (int i = 0; i < 8; ++i) {
      float v = wrow[kk + quad * 8 + i];
      bf16 hv = (bf16)v;
      bh[i] = hv;
      bl[i] = (bf16)(v - (float)hv);
    }
#pragma unroll
    for (int mt = 0; mt < 2; ++mt) {
      bf16x8 ah, al;
      const float* arow = we + (size_t)(mt * 16 + l16) * Ee + kk + quad * 8;
#pragma unroll
      for (int i = 0; i < 8; ++i) {
        float v = arow[i];
        bf16 hv = (bf16)v;
        ah[i] = hv;
        al[i] = (bf16)(v - (float)hv);
      }
      acc[mt] = MFMA16(ah, bh, acc[mt]);
      acc[mt] = MFMA16(al, bh, acc[mt]);
      acc[mt] = MFMA16(ah, bl, acc[mt]);
    }
  }
  float bias = (j < Hh) ? bz[j] : br[j - Hh];
#pragma unroll
  for (int mt = 0; mt < 2; ++mt)
#pragma unroll
    for (int r = 0; r < 4; ++r) {
      int b = mt * 16 + quad * 4 + r;
      zrwe[b * KC + j] = acc[mt][r] + bias;
    }
}

// ---------------- persistent recurrence ----------------

struct RecurArgs {
  const bf16 *Wgh, *Wgl;
  const bf16 *W2h, *W2l;
  const bf16 *Whh2, *Whl2;
  const bf16 *seh, *sel;
  const float *bg;
  const float *bhb;
  const float *zrwe;
  const float *we;
  bf16 *h_h, *h_l;
  float *c, *hl, *z, *hf;
  bf16 *hlh, *hll;
  bf16 *rweh, *rwel;
  bf16 *hs;
  unsigned *bar;
};

// grid = 256 blocks x 512 threads (8 waves). LDS 145.4KB -> 1 block/CU.
__global__ __launch_bounds__(512) void k_recur(RecurArgs a) {
  __shared__ __align__(16) bf16 sWa[2][16 * 1024];  // gates: Wg cols [512,1536)
  __shared__ __align__(16) bf16 sWx[2][16 * 1024];  // zr h-part / Wh cols [512,1536)
  __shared__ float red[8][32][17];

  int blk = blockIdx.x, tid = threadIdx.x;
  int w = tid >> 6, lane = tid & 63, l16 = lane & 15, quad = lane >> 4;

  for (int i = tid; i < 2048; i += 512) {
    int row = i >> 7, ch = i & 127, e = ch * 8;
    int d = row * 1024 + (e ^ ((row & 7) << 3));
    *(bf16x8*)&sWa[0][d] = *(const bf16x8*)&a.Wgh[(size_t)(blk * 16 + row) * KC + Ee + e];
    *(bf16x8*)&sWa[1][d] = *(const bf16x8*)&a.Wgl[(size_t)(blk * 16 + row) * KC + Ee + e];
    if (blk < 96) {
      *(bf16x8*)&sWx[0][d] = *(const bf16x8*)&a.W2h[(size_t)(blk * 16 + row) * Hh + e];
      *(bf16x8*)&sWx[1][d] = *(const bf16x8*)&a.W2l[(size_t)(blk * 16 + row) * Hh + e];
    } else if (blk < 160) {
      *(bf16x8*)&sWx[0][d] =
          *(const bf16x8*)&a.Whh2[(size_t)((blk - 96) * 16 + row) * KC + Ee + e];
      *(bf16x8*)&sWx[1][d] =
          *(const bf16x8*)&a.Whl2[(size_t)((blk - 96) * 16 + row) * KC + Ee + e];
    }
  }
  __syncthreads();

  for (int t = 0; t < Ss; ++t) {
    u32 t1 = (u32)(t + 1);
    // ===== phase A: gates tile = [se_t | h] @ Wg[blk]^T, then LSTM pointwise =====
    {
      f32x4 acc[2];
      acc[0] = (f32x4){0.f, 0.f, 0.f, 0.f};
      acc[1] = (f32x4){0.f, 0.f, 0.f, 0.f};
#pragma unroll
      for (int it = 0; it < 6; ++it) {
        int kk = w * 192 + it * 32;
        bf16x8 bh, bl;
        if (kk < Ee) {
          bh = *(const bf16x8*)&a.Wgh[(size_t)(blk * 16 + l16) * KC + kk + quad * 8];
          bl = *(const bf16x8*)&a.Wgl[(size_t)(blk * 16 + l16) * KC + kk + quad * 8];
        } else {
          int eo = (kk - Ee) + quad * 8;
          int d = l16 * 1024 + (eo ^ ((l16 & 7) << 3));
          bh = *(const bf16x8*)&sWa[0][d];
          bl = *(const bf16x8*)&sWa[1][d];
        }
#pragma unroll
        for (int mt = 0; mt < 2; ++mt) {
          int bb = mt * 16 + l16;
          bf16x8 ah, al;
          if (kk < Ee) {
            ah = *(const bf16x8*)&a.seh[(size_t)(t * Bb + bb) * Ee + kk + quad * 8];
            al = *(const bf16x8*)&a.sel[(size_t)(t * Bb + bb) * Ee + kk + quad * 8];
          } else {
            ah = cload_bf8(&a.h_h[(size_t)bb * Hh + (kk - Ee) + quad * 8]);
            al = cload_bf8(&a.h_l[(size_t)bb * Hh + (kk - Ee) + quad * 8]);
          }
          acc[mt] = MFMA16(ah, bh, acc[mt]);
          acc[mt] = MFMA16(al, bh, acc[mt]);
          acc[mt] = MFMA16(ah, bl, acc[mt]);
        }
      }
#pragma unroll
      for (int mt = 0; mt < 2; ++mt)
#pragma unroll
        for (int r = 0; r < 4; ++r) red[w][mt * 16 + quad * 4 + r][l16] = acc[mt][r];
    }
    __syncthreads();
    if (tid < 64) {
      int bb = tid >> 1, kl0 = (tid & 1) * 2;
      B2U32 ph, pl;
      F2U64 phl;
#pragma unroll
      for (int u2 = 0; u2 < 2; ++u2) {
        int kl = kl0 + u2;
        float g4[4];
#pragma unroll
        for (int s = 0; s < 4; ++s) {
          int jl = kl * 4 + s;
          float sum = a.bg[blk * 16 + jl];
#pragma unroll
          for (int w2 = 0; w2 < 8; ++w2) sum += red[w2][bb][jl];
          g4[s] = sum;
        }
        int idx = bb * Hh + blk * 4 + kl;
        float cn = sigf(g4[1]) * a.c[idx] + sigf(g4[0]) * tanhf(g4[2]);
        float hvv = sigf(g4[3]) * tanhf(cn);
        a.c[idx] = cn;
        phl.f[u2] = hvv;
        bf16 hb = (bf16)hvv;
        ph.h[u2] = hb;
        pl.h[u2] = (bf16)(hvv - (float)hb);
      }
      int base = bb * Hh + blk * 4 + kl0;
      cstore_u64(&a.hl[base], phl.u);
      cstore_u32(&a.hlh[base], ph.u);
      cstore_u32(&a.hll[base], pl.u);
    }
    bar_arrive(a.bar, 0, 256, 288, 32, 8, blk >> 5, t1);

    if (blk < 96) {
      bar_wait(a.bar, 288, t1);
      // ===== phase B: [z;r] tile = zrwe + h_lstm @ W2[blk]^T ; r*we -> rwe =====
      f32x4 acc[2];
      acc[0] = (f32x4){0.f, 0.f, 0.f, 0.f};
      acc[1] = (f32x4){0.f, 0.f, 0.f, 0.f};
#pragma unroll
      for (int it = 0; it < 4; ++it) {
        int kk = w * 128 + it * 32;
        int eo = kk + quad * 8;
        int d = l16 * 1024 + (eo ^ ((l16 & 7) << 3));
        bf16x8 bh = *(const bf16x8*)&sWx[0][d];
        bf16x8 bl = *(const bf16x8*)&sWx[1][d];
#pragma unroll
        for (int mt = 0; mt < 2; ++mt) {
          int bb = mt * 16 + l16;
          bf16x8 ah = cload_bf8(&a.hlh[(size_t)bb * Hh + kk + quad * 8]);
          bf16x8 al = cload_bf8(&a.hll[(size_t)bb * Hh + kk + quad * 8]);
          acc[mt] = MFMA16(ah, bh, acc[mt]);
          acc[mt] = MFMA16(al, bh, acc[mt]);
          acc[mt] = MFMA16(ah, bl, acc[mt]);
        }
      }
#pragma unroll
      for (int mt = 0; mt < 2; ++mt)
#pragma unroll
        for (int r = 0; r < 4; ++r) red[w][mt * 16 + quad * 4 + r][l16] = acc[mt][r];
      __syncthreads();
      if (tid < 256) {
        int bb = tid >> 3, jl0 = (tid & 7) * 2;
        float v[2];
#pragma unroll
        for (int u2 = 0; u2 < 2; ++u2) {
          int jl = jl0 + u2;
          int j = blk * 16 + jl;
          float s = a.zrwe[bb * KC + j];
#pragma unroll
          for (int w2 = 0; w2 < 8; ++w2) s += red[w2][bb][jl];
          v[u2] = s;
        }
        int j = blk * 16 + jl0;
        if (blk < 64) {
          F2U64 pz;
          pz.f[0] = sigf(v[0]);
          pz.f[1] = sigf(v[1]);
          cstore_u64(&a.z[bb * Hh + j], pz.u);
        } else {
          int e = j - Hh;
          B2U32 ph, pl;
#pragma unroll
          for (int u2 = 0; u2 < 2; ++u2) {
            float rv = sigf(v[u2]) * a.we[bb * Ee + e + u2];
            bf16 hb = (bf16)rv;
            ph.h[u2] = hb;
            pl.h[u2] = (bf16)(rv - (float)hb);
          }
          cstore_u32(&a.rweh[bb * Ee + e], ph.u);
          cstore_u32(&a.rwel[bb * Ee + e], pl.u);
        }
      }
      bar_arrive(a.bar, 320, 512, 544, 16, 6, blk >> 4, t1);
    } else if (blk < 160) {
      bar_wait(a.bar, 544, t1);
      // ===== phase C: hh tile = [rwe | h_lstm] @ Wh[jt]^T ; h update =====
      int j0 = (blk - 96) * 16;
      f32x4 acc[2];
      acc[0] = (f32x4){0.f, 0.f, 0.f, 0.f};
      acc[1] = (f32x4){0.f, 0.f, 0.f, 0.f};
#pragma unroll
      for (int it = 0; it < 6; ++it) {
        int kk = w * 192 + it * 32;
        bf16x8 bh, bl;
        if (kk < Ee) {
          bh = *(const bf16x8*)&a.Whh2[(size_t)(j0 + l16) * KC + kk + quad * 8];
          bl = *(const bf16x8*)&a.Whl2[(size_t)(j0 + l16) * KC + kk + quad * 8];
        } else {
          int eo = (kk - Ee) + quad * 8;
          int d = l16 * 1024 + (eo ^ ((l16 & 7) << 3));
          bh = *(const bf16x8*)&sWx[0][d];
          bl = *(const bf16x8*)&sWx[1][d];
        }
#pragma unroll
        for (int mt = 0; mt < 2; ++mt) {
          int bb = mt * 16 + l16;
          bf16x8 ah, al;
          if (kk < Ee) {
            ah = cload_bf8(&a.rweh[(size_t)bb * Ee + kk + quad * 8]);
            al = cload_bf8(&a.rwel[(size_t)bb * Ee + kk + quad * 8]);
          } else {
            ah = cload_bf8(&a.hlh[(size_t)bb * Hh + (kk - Ee) + quad * 8]);
            al = cload_bf8(&a.hll[(size_t)bb * Hh + (kk - Ee) + quad * 8]);
          }
          acc[mt] = MFMA16(ah, bh, acc[mt]);
          acc[mt] = MFMA16(al, bh, acc[mt]);
          acc[mt] = MFMA16(ah, bl, acc[mt]);
        }
      }
#pragma unroll
      for (int mt = 0; mt < 2; ++mt)
#pragma unroll
        for (int r = 0; r < 4; ++r) red[w][mt * 16 + quad * 4 + r][l16] = acc[mt][r];
      __syncthreads();
      if (tid < 256) {
        int bb = tid >> 3, jl0 = (tid & 7) * 2;
        int j = j0 + jl0;
        F2U64 hlp, zp;
        hlp.u = cload_u64(&a.hl[bb * Hh + j]);
        zp.u = cload_u64(&a.z[bb * Hh + j]);
        B2U32 ph, pl, phs;
        float hf2[2];
#pragma unroll
        for (int u2 = 0; u2 < 2; ++u2) {
          int jl = jl0 + u2;
          float s = a.bhb[j + u2];
#pragma unroll
          for (int w2 = 0; w2 < 8; ++w2) s += red[w2][bb][jl];
          float hhv = tanhf(s);
          float hn = (1.f - zp.f[u2]) * hlp.f[u2] + zp.f[u2] * hhv;
          hf2[u2] = hn;
          bf16 hb = (bf16)hn;
          ph.h[u2] = hb;
          pl.h[u2] = (bf16)(hn - (float)hb);
          phs.h[u2] = hb;
        }
        a.hf[bb * Hh + j] = hf2[0];
        a.hf[bb * Hh + j + 1] = hf2[1];
        cstore_u32(&a.h_h[bb * Hh + j], ph.u);
        cstore_u32(&a.h_l[bb * Hh + j], pl.u);
        *(u32*)&a.hs[((size_t)t * Bb + bb) * Hh + j] = phs.u;
      }
      bar_arrive(a.bar, 576, 832, 864, 8, 8, (blk - 96) >> 3, t1);
    }
    bar_wait(a.bar, 864, t1);
  }
}

// ---------------- final projection: out = hs @ Wo.T + bo (double-buffered pipeline) ----

__global__ __launch_bounds__(256) void k_gemm_out(const bf16* __restrict__ hs,
                                                  const float* __restrict__ Wo,
                                                  const float* __restrict__ bo,
                                                  float* __restrict__ out) {
  int id = blockIdx.x;
  int r_ = id & 7, s_ = id >> 3;
  int mi = s_ & 7;
  int ni = (s_ >> 3) * 8 + r_;
  if (ni >= Vv / 128) return;
  int m0 = mi * 128, n0 = ni * 128;

  int tid = threadIdx.x;
  int w = tid >> 6, lane = tid & 63;
  int l16 = lane & 15, quad = lane >> 4;
  int wm = w & 1, wn = w >> 1;
  int swl = ((l16 >> 1) & 3) << 3;

  __shared__ __align__(16) bf16 A_lds[2][128 * 32];
  __shared__ __align__(16) bf16 B_lds[2][128 * 32];

  f32x4 acc[4][4];
#pragma unroll
  for (int i = 0; i < 4; ++i)
#pragma unroll
    for (int j = 0; j < 4; ++j) acc[i][j] = (f32x4){0.f, 0.f, 0.f, 0.f};

  int4 ra[2];
  float4 rb[4];
  auto LOADR = [&](int kt) {
    int k0 = kt * 32;
#pragma unroll
    for (int i = 0; i < 2; ++i) {
      int cid = tid + i * 256;
      int row = cid >> 2, ch = cid & 3;
      ra[i] = *(const int4*)&hs[(size_t)(m0 + row) * Hh + k0 + ch * 8];
    }
#pragma unroll
    for (int i = 0; i < 4; ++i) {
      int cid = tid + i * 256;
      int row = cid >> 3, ch = cid & 7;
      rb[i] = *(const float4*)&Wo[(size_t)(n0 + row) * Hh + k0 + ch * 4];
    }
  };
  auto STORELDS = [&](int buf) {
#pragma unroll
    for (int i = 0; i < 2; ++i) {
      int cid = tid + i * 256;
      int row = cid >> 2, ch = cid & 3;
      int sw = ((row >> 1) & 3) << 3;
      *(int4*)&A_lds[buf][row * 32 + ((ch * 8) ^ sw)] = ra[i];
    }
#pragma unroll
    for (int i = 0; i < 4; ++i) {
      int cid = tid + i * 256;
      int row = cid >> 3, ch = cid & 7;
      int sw = ((row >> 1) & 3) << 3;
      float4 v = rb[i];
      bf16x4v bv = {(bf16)v.x, (bf16)v.y, (bf16)v.z, (bf16)v.w};
      *(bf16x4v*)&B_lds[buf][row * 32 + ((ch * 4) ^ sw)] = bv;
    }
  };

  LOADR(0);
  STORELDS(0);
  __syncthreads();
  int cur = 0;
  for (int kt = 0; kt < 32; ++kt) {
    if (kt < 31) LOADR(kt + 1);  // issue next tile's loads; latency hides under MFMA
    bf16x8 af[4], bfr[4];
#pragma unroll
    for (int i = 0; i < 4; ++i)
      af[i] = *(const bf16x8*)&A_lds[cur][(wm * 64 + i * 16 + l16) * 32 + ((quad * 8) ^ swl)];
#pragma unroll
    for (int j = 0; j < 4; ++j)
      bfr[j] = *(const bf16x8*)&B_lds[cur][(wn * 64 + j * 16 + l16) * 32 + ((quad * 8) ^ swl)];
#pragma unroll
    for (int i = 0; i < 4; ++i)
#pragma unroll
      for (int j = 0; j < 4; ++j) acc[i][j] = MFMA16(af[i], bfr[j], acc[i][j]);
    if (kt < 31) {
      STORELDS(cur ^ 1);  // other buffer: safe while peers still read buf[cur]
      __syncthreads();
      cur ^= 1;
    }
  }

#pragma unroll
  for (int i = 0; i < 4; ++i)
#pragma unroll
    for (int j = 0; j < 4; ++j)
#pragma unroll
      for (int r = 0; r < 4; ++r) {
        int m = m0 + wm * 64 + i * 16 + quad * 4 + r;
        int n = n0 + wn * 64 + j * 16 + l16;
        out[(size_t)m * Vv + n] = acc[i][j][r] + bo[n];
      }
}

__global__ void k_copy_hc(const float* __restrict__ h_f32, const float* __restrict__ c_f32,
                          float* __restrict__ out) {
  int i = blockIdx.x * 256 + threadIdx.x;
  size_t base = (size_t)Ss * Bb * Vv;
  out[base + i] = h_f32[i];
  out[base + Bb * Hh + i] = c_f32[i];
}

// ---------------- host ----------------

extern "C" void kernel_launch(void* const* d_in, const int* in_sizes, int n_in,
                              void* d_out, int out_size, void* d_ws, size_t ws_size,
                              hipStream_t stream) {
  const int* word = (const int*)d_in[0];
  const int* seq = (const int*)d_in[1];
  const float* emb = (const float*)d_in[2];
  const float* Wl = (const float*)d_in[3];
  const float* bl = (const float*)d_in[4];
  const float* Wih = (const float*)d_in[5];
  const float* Whh = (const float*)d_in[6];
  const float* bih = (const float*)d_in[7];
  const float* bhh = (const float*)d_in[8];
  const float* Wz = (const float*)d_in[9];
  const float* bz = (const float*)d_in[10];
  const float* Wr = (const float*)d_in[11];
  const float* br = (const float*)d_in[12];
  const float* Wh = (const float*)d_in[13];
  const float* bh = (const float*)d_in[14];
  const float* Wo = (const float*)d_in[15];
  const float* bo = (const float*)d_in[16];
  float* out = (float*)d_out;

  char* p = (char*)d_ws;
  auto alloc = [&](size_t bytes) -> char* {
    char* q = p;
    p += (bytes + 255) & ~(size_t)255;
    return q;
  };
  unsigned* bar = (unsigned*)alloc(4096);
  float* we_f32 = (float*)alloc(Bb * Ee * 4);
  float* zrwe = (float*)alloc(Bb * KC * 4);
  float* c_f32 = (float*)alloc(Bb * Hh * 4);
  float* hl_f32 = (float*)alloc(Bb * Hh * 4);
  float* z_f32 = (float*)alloc(Bb * Hh * 4);
  float* hf_f32 = (float*)alloc(Bb * Hh * 4);
  bf16* h_h = (bf16*)alloc(Bb * Hh * 2);
  bf16* h_l = (bf16*)alloc(Bb * Hh * 2);
  bf16* hlh = (bf16*)alloc(Bb * Hh * 2);
  bf16* hll = (bf16*)alloc(Bb * Hh * 2);
  bf16* rweh = (bf16*)alloc(Bb * Ee * 2);
  bf16* rwel = (bf16*)alloc(Bb * Ee * 2);
  bf16* se_h = (bf16*)alloc((size_t)Ss * Bb * Ee * 2);
  bf16* se_l = (bf16*)alloc((size_t)Ss * Bb * Ee * 2);
  bf16* hs_b = (bf16*)alloc((size_t)Ss * Bb * Hh * 2);
  bf16* Wgh = (bf16*)alloc((size_t)4 * Hh * KC * 2);
  bf16* Wgl = (bf16*)alloc((size_t)4 * Hh * KC * 2);
  bf16* W2h = (bf16*)alloc((size_t)KC * Hh * 2);
  bf16* W2l = (bf16*)alloc((size_t)KC * Hh * 2);
  bf16* Whh2 = (bf16*)alloc((size_t)Hh * KC * 2);
  bf16* Whl2 = (bf16*)alloc((size_t)Hh * KC * 2);
  float* bg = (float*)alloc((size_t)4 * Hh * 4);

  dim3 blk(256);
  hipMemsetAsync(bar, 0, 4096, stream);
  k_conv_gates<<<dim3(6, 4096), blk, 0, stream>>>(Wih, Whh, bih, bhh, Wgh, Wgl, bg);
  k_conv_zr2<<<dim3(4, 1536), blk, 0, stream>>>(Wz, Wr, W2h, W2l);
  k_conv_wh<<<dim3(6, 1024), blk, 0, stream>>>(Wh, Whh2, Whl2);
  k_gather_we<<<dim3(2, 32), blk, 0, stream>>>(word, emb, we_f32);
  k_gather_se<<<dim3(2, Ss * Bb), blk, 0, stream>>>(seq, emb, se_h, se_l);
  k_init_h0<<<8192, blk, 0, stream>>>(we_f32, Wl, bl, c_f32, h_h, h_l);
  k_zrwe<<<24, blk, 0, stream>>>(we_f32, Wz, Wr, bz, br, zrwe);

  RecurArgs ra;
  ra.Wgh = Wgh; ra.Wgl = Wgl;
  ra.W2h = W2h; ra.W2l = W2l;
  ra.Whh2 = Whh2; ra.Whl2 = Whl2;
  ra.seh = se_h; ra.sel = se_l;
  ra.bg = bg; ra.bhb = bh; ra.zrwe = zrwe; ra.we = we_f32;
  ra.h_h = h_h; ra.h_l = h_l;
  ra.c = c_f32; ra.hl = hl_f32; ra.z = z_f32; ra.hf = hf_f32;
  ra.hlh = hlh; ra.hll = hll;
  ra.rweh = rweh; ra.rwel = rwel;
  ra.hs = hs_b;
  ra.bar = bar;
  k_recur<<<256, dim3(512), 0, stream>>>(ra);

  k_gemm_out<<<2048, blk, 0, stream>>>(hs_b, Wo, bo, out);
  k_copy_hc<<<128, blk, 0, stream>>>(hf_f32, c_f32, out);
}